// Round 11
// baseline (513.775 us; speedup 1.0000x reference)
//
#include <hip/hip_runtime.h>
#include <math.h>

typedef unsigned short us;
typedef __attribute__((ext_vector_type(8))) short frag8;
typedef __attribute__((ext_vector_type(4))) float f4;

#define B_   2
#define T_   1024
#define DM_  1024
#define D_   2048
#define N_   16
#define DTR_ 128
#define NDBC 160           // DTR + 2N
#define ROWS (B_*T_)       // 2048
#define EPS_ 1e-6f
#define NCH  32            // scan chunks per channel
#define CLEN (T_/NCH)      // 32 steps per chunk

__device__ __forceinline__ float us2f(us s){
    return __uint_as_float(((unsigned int)s) << 16);
}
__device__ __forceinline__ us f2us(float f){   // RTN-even fp32->bf16
    unsigned int u = __float_as_uint(f);
    return (us)((u + 0x7FFF + ((u >> 16) & 1)) >> 16);
}

// one DPP row_ror:K accumulate step (dpp_ctrl must be a literal constant)
template<int CTRL>
__device__ __forceinline__ float dpp_add(float x){
    int t = __builtin_amdgcn_update_dpp(0, __float_as_int(x), CTRL, 0xF, 0xF, true);
    return x + __int_as_float(t);
}
// 16-lane sum via DPP row_ror (VALU pipe, no DS ops). (i+k)%16 cyclic butterfly.
__device__ __forceinline__ float sum16_dpp(float x){
    x = dpp_add<0x128>(x);   // row_ror:8
    x = dpp_add<0x124>(x);   // row_ror:4
    x = dpp_add<0x122>(x);   // row_ror:2
    x = dpp_add<0x121>(x);   // row_ror:1
    return x;
}

// ---- combined weight prep: 4 matrices fp32 [R][C] -> bf16 [C][R] ----
// tile counts: in_W 4096 | out_W 2048 | dbc_W 320 | dup_W 256  (total 6720)
__global__ __launch_bounds__(256) void prep_weights(
    const float* __restrict__ in_W,  const float* __restrict__ out_W,
    const float* __restrict__ dbc_W, const float* __restrict__ dup_W,
    us* __restrict__ inWt, us* __restrict__ outWt,
    us* __restrict__ dbcWt, us* __restrict__ dupWt)
{
    __shared__ us tile[32][33];
    int bid = blockIdx.x;
    const float* src; us* dst; int C, R, TX, rel;
    if (bid < 4096)      { src = in_W;  dst = inWt;  R = 1024; C = 4096; TX = 128; rel = bid; }
    else if (bid < 6144) { src = out_W; dst = outWt; R = 2048; C = 1024; TX = 32;  rel = bid - 4096; }
    else if (bid < 6464) { src = dbc_W; dst = dbcWt; R = 2048; C = 160;  TX = 5;   rel = bid - 6144; }
    else                 { src = dup_W; dst = dupWt; R = 128;  C = 2048; TX = 64;  rel = bid - 6464; }
    int c0 = (rel % TX) * 32, r0 = (rel / TX) * 32;
    int tx = threadIdx.x, ty = threadIdx.y;   // 32 x 8
    for (int i = ty; i < 32; i += 8)
        tile[i][tx] = f2us(src[(size_t)(r0 + i) * C + c0 + tx]);
    __syncthreads();
    for (int i = ty; i < 32; i += 8)
        dst[(size_t)(c0 + i) * R + r0 + tx] = tile[tx][i];
}

// ------------- bf16 [R][C] -> bf16 [C][R] (dims multiples of 32) -------------
__global__ __launch_bounds__(256) void transpose_us(const us* __restrict__ in,
                                                    us* __restrict__ out, int R, int C)
{
    __shared__ us tile[32][33];
    int c0 = blockIdx.x * 32, r0 = blockIdx.y * 32;
    int tx = threadIdx.x, ty = threadIdx.y;   // 32 x 8
    for (int i = ty; i < 32; i += 8)
        tile[i][tx] = in[(size_t)(r0 + i) * C + c0 + tx];
    __syncthreads();
    for (int i = ty; i < 32; i += 8)
        out[(size_t)(c0 + i) * R + r0 + tx] = tile[tx][i];
}

// ---------------- fused RMSNorm -> bf16 h, one block per row ----------------
__global__ __launch_bounds__(256) void rmshbf_kernel(const float* __restrict__ x,
                                                     const float* __restrict__ rms_w,
                                                     us* __restrict__ hbf)
{
    const int row = blockIdx.x;
    const float* xr = x + (size_t)row * DM_;
    const int tid = threadIdx.x;
    float vals[4], ss = 0.f;
#pragma unroll
    for (int i = 0; i < 4; ++i) { vals[i] = xr[tid + i*256]; ss += vals[i]*vals[i]; }
#pragma unroll
    for (int off = 32; off >= 1; off >>= 1) ss += __shfl_xor(ss, off, 64);
    __shared__ float red[4];
    if ((tid & 63) == 0) red[tid >> 6] = ss;
    __syncthreads();
    float scale = rsqrtf((red[0]+red[1]+red[2]+red[3]) / (float)DM_ + EPS_);
#pragma unroll
    for (int i = 0; i < 4; ++i)
        hbf[(size_t)row * DM_ + tid + i*256] = f2us(vals[i] * scale * rms_w[tid + i*256]);
}

// ---------- MFMA GEMM: C[M,N] = A[M,K](bf16) * Bt[N,K](bf16)^T + bias --------
// 128x128 tile / 4 waves; wave 64x64 via 4x4 mfma_f32_16x16x32_bf16.
// RB: bias indexed by M-row (for transposed-output GEMMs) else by N-col.
// EPI 0: plain fp32. 1: softplus fp32. 2: +resid fp32. 3: fp32 + bf16 aux col<DTR.
template<int EPI, bool RB>
__global__ __launch_bounds__(256) void mgemm(
    const us*    __restrict__ A,     // [M][K]
    const us*    __restrict__ Bt,    // [N][K]
    const float* __restrict__ bias,
    float*       __restrict__ Cf,
    us*          __restrict__ Caux,  // EPI==3
    const float* __restrict__ resid, // EPI==2
    int M, int N, int K)
{
    __shared__ us As[128][72];
    __shared__ us Bs[128][72];
    const int tid = threadIdx.x;
    const int bm = blockIdx.y * 128;
    const int bn = blockIdx.x * 128;
    const int w = tid >> 6, lane = tid & 63;
    const int wr = w >> 1, wc = w & 1;
    const int m16 = lane & 15, quad = lane >> 4;

    f4 acc[4][4];
#pragma unroll
    for (int i = 0; i < 4; ++i)
#pragma unroll
        for (int j = 0; j < 4; ++j)
            acc[i][j] = (f4){0.f, 0.f, 0.f, 0.f};

    for (int k0 = 0; k0 < K; k0 += 64) {
        __syncthreads();
#pragma unroll
        for (int i = 0; i < 4; ++i) {
            int chunk = i * 256 + tid;           // 1024 chunks of 16B
            int row = chunk >> 3, c8 = (chunk & 7) * 8;
            int4 va = *(const int4*)(A + (size_t)(bm + row) * K + k0 + c8);
            *(int4*)&As[row][c8] = va;
            int nrow = bn + row;
            int4 vb = make_int4(0, 0, 0, 0);
            if (nrow < N) vb = *(const int4*)(Bt + (size_t)nrow * K + k0 + c8);
            *(int4*)&Bs[row][c8] = vb;
        }
        __syncthreads();
#pragma unroll
        for (int ks = 0; ks < 64; ks += 32) {
            frag8 af[4], bfr[4];
#pragma unroll
            for (int i = 0; i < 4; ++i)
                af[i] = *(const frag8*)&As[wr*64 + i*16 + m16][ks + quad*8];
#pragma unroll
            for (int j = 0; j < 4; ++j)
                bfr[j] = *(const frag8*)&Bs[wc*64 + j*16 + m16][ks + quad*8];
#pragma unroll
            for (int i = 0; i < 4; ++i)
#pragma unroll
                for (int j = 0; j < 4; ++j)
                    acc[i][j] = __builtin_amdgcn_mfma_f32_16x16x32_bf16(af[i], bfr[j], acc[i][j], 0, 0, 0);
        }
    }

#pragma unroll
    for (int i = 0; i < 4; ++i) {
#pragma unroll
        for (int j = 0; j < 4; ++j) {
            int col = bn + wc*64 + j*16 + m16;
            if (col >= N) continue;
            float bvc = RB ? 0.f : bias[col];
#pragma unroll
            for (int r = 0; r < 4; ++r) {
                int row = bm + wr*64 + i*16 + quad*4 + r;
                float v = acc[i][j][r] + (RB ? bias[row] : bvc);
                if constexpr (EPI == 1) v = fmaxf(v, 0.f) + log1pf(expf(-fabsf(v)));
                if constexpr (EPI == 2) v += resid[(size_t)row * N + col];
                Cf[(size_t)row * N + col] = v;
                if constexpr (EPI == 3) {
                    if (col < DTR_) Caux[(size_t)row * DTR_ + col] = f2us(v);
                }
            }
        }
    }
}

// ------- depthwise causal conv (K=4) + SiLU, dual-layout bf16 output --------
// reads x1pre [ROWS][D]; writes x1cb [rows][D] and x1tb [d][rows] (LDS tile).
__global__ __launch_bounds__(256) void conv_silu_kernel(
    const float* __restrict__ x1pre,
    const float* __restrict__ cw,
    const float* __restrict__ cb,
    us*          __restrict__ x1cb,
    us*          __restrict__ x1tb)
{
    __shared__ us tile[32][33];
    const int tx = threadIdx.x, ty = threadIdx.y;   // 32 x 8
    const int d0 = blockIdx.x * 32, r0 = blockIdx.y * 32;
    const int d = d0 + tx;
    const float w0 = cw[d*4+0], w1 = cw[d*4+1], w2 = cw[d*4+2], w3 = cw[d*4+3];
    const float bias = cb[d];
    for (int i = ty; i < 32; i += 8) {
        int row = r0 + i;
        int t = row & (T_ - 1);
        const float* base = x1pre + (size_t)row * D_ + d;
        float acc = bias;
        acc = fmaf(w3, base[0], acc);
        if (t >= 1) acc = fmaf(w2, base[-D_],   acc);
        if (t >= 2) acc = fmaf(w1, base[-2*D_], acc);
        if (t >= 3) acc = fmaf(w0, base[-3*D_], acc);
        float sg = 1.f / (1.f + __expf(-acc));
        us uv = f2us(acc * sg);
        x1cb[(size_t)row * D_ + d] = uv;
        tile[i][tx] = uv;
    }
    __syncthreads();
    for (int i = ty; i < 32; i += 8)
        x1tb[(size_t)(d0 + i) * ROWS + r0 + tx] = tile[tx][i];
}

// ------- chunked selective scan + gate, one block per (b,d) channel ----------
// 512 threads = NCH(32) chunks x N(16). Unit-stride streams (delta_t/g_t fp32,
// x1tb bf16, y_t bf16, all [d][rows]); dx=delta*x pre-staged; DPP reduction.
__global__ __launch_bounds__(512) void scan_block_kernel(
    const float* __restrict__ delta_t,
    const us*    __restrict__ x1tb,
    const float* __restrict__ dbc,    // [...,128:144]=Bm [...,144:160]=Cm
    const float* __restrict__ A_log,
    const float* __restrict__ g_t,
    us*          __restrict__ y_t)
{
    __shared__ float dvs[T_ + NCH];   // swizzle f(t)=t+(t>>6)
    __shared__ float dxs[T_ + NCH];
    __shared__ float gs [T_ + NCH];
    __shared__ float ys [T_ + NCH];
    __shared__ float Pl[NCH][N_];
    __shared__ float Sl[NCH][N_];

    const int tid = threadIdx.x;
    const int d = blockIdx.x & (D_ - 1);
    const int b = blockIdx.x >> 11;
    const int n = tid & 15;
    const int c = tid >> 4;            // chunk 0..31
    const size_t rb = (size_t)b * T_;
    const size_t cb0 = (size_t)d * ROWS + rb;

    {   // coalesced staging: 2 elems/thread
        int i = tid * 2;
        int fi = i + (i >> 6);
        float2 dv2 = *(const float2*)&delta_t[cb0 + i];
        float2 g2  = *(const float2*)&g_t    [cb0 + i];
        ushort2 ux = *(const ushort2*)&x1tb  [cb0 + i];
        dvs[fi+0] = dv2.x;              dvs[fi+1] = dv2.y;
        dxs[fi+0] = dv2.x * us2f(ux.x); dxs[fi+1] = dv2.y * us2f(ux.y);
        gs [fi+0] = g2.x;               gs [fi+1] = g2.y;
    }
    const float a_coef = -__expf(A_log[d * N_ + n]);
    __syncthreads();

    float P = 1.f, S = 0.f;
    const int t0 = c * CLEN;
#pragma unroll 4
    for (int j = 0; j < CLEN; ++j) {
        int t = t0 + j;
        int ft = t + (t >> 6);
        float Bv = dbc[(rb + t) * NDBC + DTR_ + n];
        float a = __expf(dvs[ft] * a_coef);
        P *= a;
        S = fmaf(a, S, dxs[ft] * Bv);
    }
    Pl[c][n] = P;
    Sl[c][n] = S;
    __syncthreads();

    float h = 0.f;
    for (int c2 = 0; c2 < c; ++c2)
        h = fmaf(Pl[c2][n], h, Sl[c2][n]);

#pragma unroll 4
    for (int j = 0; j < CLEN; ++j) {
        int t = t0 + j;
        int ft = t + (t >> 6);
        size_t r = rb + t;
        float Bv = dbc[r * NDBC + DTR_ + n];
        float Cv = dbc[r * NDBC + DTR_ + N_ + n];
        float a = __expf(dvs[ft] * a_coef);
        h = fmaf(a, h, dxs[ft] * Bv);
        float part = sum16_dpp(h * Cv);
        if (n == 0) {
            float g = gs[ft];
            float sg = 1.f / (1.f + __expf(-g));
            ys[ft] = part * g * sg;
        }
    }
    __syncthreads();
    {   // coalesced bf16 store of y
        int i = tid * 2;
        int fi = i + (i >> 6);
        ushort2 uy;
        uy.x = f2us(ys[fi+0]); uy.y = f2us(ys[fi+1]);
        *(ushort2*)&y_t[cb0 + i] = uy;
    }
}

extern "C" void kernel_launch(void* const* d_in, const int* in_sizes, int n_in,
                              void* d_out, int out_size, void* d_ws, size_t ws_size,
                              hipStream_t stream)
{
    const float* x      = (const float*)d_in[0];
    const float* rms_w  = (const float*)d_in[1];
    const float* in_W   = (const float*)d_in[2];
    const float* in_b   = (const float*)d_in[3];
    const float* conv_w = (const float*)d_in[4];
    const float* conv_b = (const float*)d_in[5];
    const float* A_log  = (const float*)d_in[6];
    const float* dbc_W  = (const float*)d_in[7];
    const float* dbc_b  = (const float*)d_in[8];
    const float* dup_W  = (const float*)d_in[9];
    const float* dup_b  = (const float*)d_in[10];
    const float* out_W  = (const float*)d_in[11];
    const float* out_b  = (const float*)d_in[12];
    float* out = (float*)d_out;

    // ---- workspace layout (~83 MB; >=94 MB proven available in R1) ----
    float* ws      = (float*)d_ws;
    float* x1pre   = ws;                           // 16 MB, dead after conv
    float* g_t     = x1pre  + (size_t)ROWS*D_;     // 16 MB [d][rows]
    float* dbcB    = g_t    + (size_t)ROWS*D_;     // 1.3 MB
    float* delta_t = dbcB   + (size_t)ROWS*NDBC;   // 16 MB [d][rows]
    us* hbf   = (us*)(delta_t + (size_t)ROWS*D_);  // 4 MB
    us* x1cb  = hbf   + (size_t)ROWS*DM_;          // 8 MB [rows][D], dead after dbc-GEMM
    us* x1tb  = x1cb  + (size_t)ROWS*D_;           // 8 MB [d][rows]
    us* dtrb  = x1tb  + (size_t)ROWS*D_;           // 0.5 MB [rows][DTR]
    us* inWt  = dtrb  + (size_t)ROWS*DTR_;         // 8 MB  [4096][1024]
    us* dbcWt = inWt  + (size_t)2*D_*DM_;          // 0.64 MB [160][2048]
    us* dupWt = dbcWt + (size_t)NDBC*D_;           // 0.5 MB [2048][128]
    us* outWt = dupWt + (size_t)D_*DTR_;           // 4 MB  [1024][2048]
    us* y_t   = (us*)x1pre;                        // alias (x1pre dead), [d][rows]
    us* ybf   = x1cb;                              // alias (x1cb dead), [rows][D]

    dim3 tb(32, 8);
    // 1. weight prep (all four transposes in one launch)
    prep_weights<<<6720, tb, 0, stream>>>(in_W, out_W, dbc_W, dup_W,
                                          inWt, outWt, dbcWt, dupWt);
    // 2. fused rmsnorm -> hbf (bf16)
    rmshbf_kernel<<<ROWS, 256, 0, stream>>>(x, rms_w, hbf);
    // 3. x1pre = h @ in_W[:, :D] + in_b[:D]        [2048 x 2048], K=1024
    mgemm<0,false><<<dim3(16, 16), 256, 0, stream>>>(
        hbf, inWt, in_b, x1pre, nullptr, nullptr, ROWS, D_, DM_);
    // 4. g_t = (in_W[:, D:]^T @ h^T) + in_b[D:]    [2048 x 2048], K=1024 (transposed out)
    mgemm<0,true><<<dim3(16, 16), 256, 0, stream>>>(
        inWt + (size_t)D_*DM_, hbf, in_b + D_, g_t, nullptr, nullptr, D_, ROWS, DM_);
    // 5. conv + silu -> x1cb [rows][D] + x1tb [d][rows]
    conv_silu_kernel<<<dim3(D_/32, ROWS/32), tb, 0, stream>>>(
        x1pre, conv_w, conv_b, x1cb, x1tb);
    // 6. dbc = x1c @ dbc_W + dbc_b   [2048 x 160], K=2048 (+bf16 aux cols<128)
    mgemm<3,false><<<dim3(2, 16), 256, 0, stream>>>(
        x1cb, dbcWt, dbc_b, dbcB, dtrb, nullptr, ROWS, NDBC, D_);
    // 7. delta_t = softplus(dup_W^T @ dtr^T + dup_b)   [2048 x 2048], K=128 (transposed out)
    mgemm<1,true><<<dim3(16, 16), 256, 0, stream>>>(
        dupWt, dtrb, dup_b, delta_t, nullptr, nullptr, D_, ROWS, DTR_);
    // 8. chunked selective scan + gate -> y_t [d][rows]
    scan_block_kernel<<<B_*D_, 512, 0, stream>>>(delta_t, x1tb, dbcB, A_log, g_t, y_t);
    // 9. y_t -> ybf [rows][D]
    transpose_us<<<dim3(ROWS/32, D_/32), tb, 0, stream>>>(y_t, ybf, D_, ROWS);
    // 10. out = y @ out_W + out_b + residual   [2048 x 1024], K=2048
    mgemm<2,false><<<dim3(8, 16), 256, 0, stream>>>(
        ybf, outWt, out_b, out, nullptr, x, ROWS, DM_, D_);
}

// Round 12
// 401.401 us; speedup vs baseline: 1.2800x; 1.2800x over previous
//
#include <hip/hip_runtime.h>
#include <math.h>

typedef unsigned short us;
typedef __attribute__((ext_vector_type(8))) short frag8;
typedef __attribute__((ext_vector_type(4))) float f4;

#define B_   2
#define T_   1024
#define DM_  1024
#define D_   2048
#define N_   16
#define DTR_ 128
#define NDBC 160           // DTR + 2N
#define ROWS (B_*T_)       // 2048
#define EPS_ 1e-6f
#define NCH  32            // scan chunks per channel
#define CLEN (T_/NCH)      // 32 steps per chunk

__device__ __forceinline__ float us2f(us s){
    return __uint_as_float(((unsigned int)s) << 16);
}
__device__ __forceinline__ us f2us(float f){   // RTN-even fp32->bf16
    unsigned int u = __float_as_uint(f);
    return (us)((u + 0x7FFF + ((u >> 16) & 1)) >> 16);
}

// one DPP row_ror:K accumulate step (dpp_ctrl must be a literal constant)
template<int CTRL>
__device__ __forceinline__ float dpp_add(float x){
    int t = __builtin_amdgcn_update_dpp(0, __float_as_int(x), CTRL, 0xF, 0xF, true);
    return x + __int_as_float(t);
}
// 16-lane sum via DPP row_ror (VALU pipe, no DS ops)
__device__ __forceinline__ float sum16_dpp(float x){
    x = dpp_add<0x128>(x);   // row_ror:8
    x = dpp_add<0x124>(x);   // row_ror:4
    x = dpp_add<0x122>(x);   // row_ror:2
    x = dpp_add<0x121>(x);   // row_ror:1
    return x;
}

// ---- combined weight prep: 4 matrices fp32 [R][C] -> bf16 [C][R] ----
__global__ __launch_bounds__(256) void prep_weights(
    const float* __restrict__ in_W,  const float* __restrict__ out_W,
    const float* __restrict__ dbc_W, const float* __restrict__ dup_W,
    us* __restrict__ inWt, us* __restrict__ outWt,
    us* __restrict__ dbcWt, us* __restrict__ dupWt)
{
    __shared__ us tile[32][33];
    int bid = blockIdx.x;
    const float* src; us* dst; int C, R, TX, rel;
    if (bid < 4096)      { src = in_W;  dst = inWt;  R = 1024; C = 4096; TX = 128; rel = bid; }
    else if (bid < 6144) { src = out_W; dst = outWt; R = 2048; C = 1024; TX = 32;  rel = bid - 4096; }
    else if (bid < 6464) { src = dbc_W; dst = dbcWt; R = 2048; C = 160;  TX = 5;   rel = bid - 6144; }
    else                 { src = dup_W; dst = dupWt; R = 128;  C = 2048; TX = 64;  rel = bid - 6464; }
    int c0 = (rel % TX) * 32, r0 = (rel / TX) * 32;
    int tx = threadIdx.x, ty = threadIdx.y;   // 32 x 8
    for (int i = ty; i < 32; i += 8)
        tile[i][tx] = f2us(src[(size_t)(r0 + i) * C + c0 + tx]);
    __syncthreads();
    for (int i = ty; i < 32; i += 8)
        dst[(size_t)(c0 + i) * R + r0 + tx] = tile[tx][i];
}

// ------------- bf16 [R][C] -> bf16 [C][R] (dims multiples of 32) -------------
__global__ __launch_bounds__(256) void transpose_us(const us* __restrict__ in,
                                                    us* __restrict__ out, int R, int C)
{
    __shared__ us tile[32][33];
    int c0 = blockIdx.x * 32, r0 = blockIdx.y * 32;
    int tx = threadIdx.x, ty = threadIdx.y;   // 32 x 8
    for (int i = ty; i < 32; i += 8)
        tile[i][tx] = in[(size_t)(r0 + i) * C + c0 + tx];
    __syncthreads();
    for (int i = ty; i < 32; i += 8)
        out[(size_t)(c0 + i) * R + r0 + tx] = tile[tx][i];
}

// ---------------- fused RMSNorm -> bf16 h, one block per row ----------------
__global__ __launch_bounds__(256) void rmshbf_kernel(const float* __restrict__ x,
                                                     const float* __restrict__ rms_w,
                                                     us* __restrict__ hbf)
{
    const int row = blockIdx.x;
    const float* xr = x + (size_t)row * DM_;
    const int tid = threadIdx.x;
    float vals[4], ss = 0.f;
#pragma unroll
    for (int i = 0; i < 4; ++i) { vals[i] = xr[tid + i*256]; ss += vals[i]*vals[i]; }
#pragma unroll
    for (int off = 32; off >= 1; off >>= 1) ss += __shfl_xor(ss, off, 64);
    __shared__ float red[4];
    if ((tid & 63) == 0) red[tid >> 6] = ss;
    __syncthreads();
    float scale = rsqrtf((red[0]+red[1]+red[2]+red[3]) / (float)DM_ + EPS_);
#pragma unroll
    for (int i = 0; i < 4; ++i)
        hbf[(size_t)row * DM_ + tid + i*256] = f2us(vals[i] * scale * rms_w[tid + i*256]);
}

// ---------- MFMA GEMM: C[M,N] = A[M,K](bf16) * Bt[N,K](bf16)^T + bias --------
// 128x128 tile / 4 waves; wave 64x64 via 4x4 mfma_f32_16x16x32_bf16.
// RB: bias indexed by M-row (for transposed-output GEMMs) else by N-col.
// EPI 0: plain fp32. 1: CHEAP softplus fp32. 2: +resid fp32.
// EPI 3: fp32 + bf16 aux col<DTR. EPI 4: col<D -> fp32 Cf[row][col];
//        col>=D -> bf16 Caux[row][col-D]  (fused in_proj, both row-major).
template<int EPI, bool RB>
__global__ __launch_bounds__(256) void mgemm(
    const us*    __restrict__ A,     // [M][K]
    const us*    __restrict__ Bt,    // [N][K]
    const float* __restrict__ bias,
    float*       __restrict__ Cf,
    us*          __restrict__ Caux,
    const float* __restrict__ resid, // EPI==2
    int M, int N, int K)
{
    __shared__ us As[128][72];
    __shared__ us Bs[128][72];
    const int tid = threadIdx.x;
    const int bm = blockIdx.y * 128;
    const int bn = blockIdx.x * 128;
    const int w = tid >> 6, lane = tid & 63;
    const int wr = w >> 1, wc = w & 1;
    const int m16 = lane & 15, quad = lane >> 4;

    f4 acc[4][4];
#pragma unroll
    for (int i = 0; i < 4; ++i)
#pragma unroll
        for (int j = 0; j < 4; ++j)
            acc[i][j] = (f4){0.f, 0.f, 0.f, 0.f};

    for (int k0 = 0; k0 < K; k0 += 64) {
        __syncthreads();
#pragma unroll
        for (int i = 0; i < 4; ++i) {
            int chunk = i * 256 + tid;           // 1024 chunks of 16B
            int row = chunk >> 3, c8 = (chunk & 7) * 8;
            int4 va = *(const int4*)(A + (size_t)(bm + row) * K + k0 + c8);
            *(int4*)&As[row][c8] = va;
            int nrow = bn + row;
            int4 vb = make_int4(0, 0, 0, 0);
            if (nrow < N) vb = *(const int4*)(Bt + (size_t)nrow * K + k0 + c8);
            *(int4*)&Bs[row][c8] = vb;
        }
        __syncthreads();
#pragma unroll
        for (int ks = 0; ks < 64; ks += 32) {
            frag8 af[4], bfr[4];
#pragma unroll
            for (int i = 0; i < 4; ++i)
                af[i] = *(const frag8*)&As[wr*64 + i*16 + m16][ks + quad*8];
#pragma unroll
            for (int j = 0; j < 4; ++j)
                bfr[j] = *(const frag8*)&Bs[wc*64 + j*16 + m16][ks + quad*8];
#pragma unroll
            for (int i = 0; i < 4; ++i)
#pragma unroll
                for (int j = 0; j < 4; ++j)
                    acc[i][j] = __builtin_amdgcn_mfma_f32_16x16x32_bf16(af[i], bfr[j], acc[i][j], 0, 0, 0);
        }
    }

#pragma unroll
    for (int i = 0; i < 4; ++i) {
#pragma unroll
        for (int j = 0; j < 4; ++j) {
            int col = bn + wc*64 + j*16 + m16;
            if (col >= N) continue;
            float bvc = RB ? 0.f : bias[col];
#pragma unroll
            for (int r = 0; r < 4; ++r) {
                int row = bm + wr*64 + i*16 + quad*4 + r;
                float v = acc[i][j][r] + (RB ? bias[row] : bvc);
                if constexpr (EPI == 1) {
                    v = fmaxf(v, 0.f) + __logf(1.f + __expf(-fabsf(v)));
                    Cf[(size_t)row * N + col] = v;
                } else if constexpr (EPI == 2) {
                    v += resid[(size_t)row * N + col];
                    Cf[(size_t)row * N + col] = v;
                } else if constexpr (EPI == 3) {
                    Cf[(size_t)row * N + col] = v;
                    if (col < DTR_) Caux[(size_t)row * DTR_ + col] = f2us(v);
                } else if constexpr (EPI == 4) {
                    if (col < D_) Cf  [(size_t)row * D_ + col]        = v;
                    else          Caux[(size_t)row * D_ + (col - D_)] = f2us(v);
                } else {
                    Cf[(size_t)row * N + col] = v;
                }
            }
        }
    }
}

// --- depthwise causal conv (K=4) + SiLU, dual-layout x1 out + g transpose ---
// reads x1pre [ROWS][D] fp32 and g_rm [ROWS][D] bf16;
// writes x1cb [rows][D], x1tb [d][rows], g_t [d][rows] (all bf16).
__global__ __launch_bounds__(256) void conv_silu_kernel(
    const float* __restrict__ x1pre,
    const us*    __restrict__ g_rm,
    const float* __restrict__ cw,
    const float* __restrict__ cb,
    us*          __restrict__ x1cb,
    us*          __restrict__ x1tb,
    us*          __restrict__ g_t)
{
    __shared__ us tileX[32][33];
    __shared__ us tileG[32][33];
    const int tx = threadIdx.x, ty = threadIdx.y;   // 32 x 8
    const int d0 = blockIdx.x * 32, r0 = blockIdx.y * 32;
    const int d = d0 + tx;
    const float w0 = cw[d*4+0], w1 = cw[d*4+1], w2 = cw[d*4+2], w3 = cw[d*4+3];
    const float bias = cb[d];
    for (int i = ty; i < 32; i += 8) {
        int row = r0 + i;
        int t = row & (T_ - 1);
        const float* base = x1pre + (size_t)row * D_ + d;
        float acc = bias;
        acc = fmaf(w3, base[0], acc);
        if (t >= 1) acc = fmaf(w2, base[-D_],   acc);
        if (t >= 2) acc = fmaf(w1, base[-2*D_], acc);
        if (t >= 3) acc = fmaf(w0, base[-3*D_], acc);
        float sg = 1.f / (1.f + __expf(-acc));
        us uv = f2us(acc * sg);
        x1cb[(size_t)row * D_ + d] = uv;
        tileX[i][tx] = uv;
        tileG[i][tx] = g_rm[(size_t)row * D_ + d];
    }
    __syncthreads();
    for (int i = ty; i < 32; i += 8) {
        x1tb[(size_t)(d0 + i) * ROWS + r0 + tx] = tileX[tx][i];
        g_t [(size_t)(d0 + i) * ROWS + r0 + tx] = tileG[tx][i];
    }
}

// ------- chunked selective scan + gate, one block per (b,d) channel ----------
__global__ __launch_bounds__(512) void scan_block_kernel(
    const float* __restrict__ delta_t,
    const us*    __restrict__ x1tb,
    const float* __restrict__ dbc,    // [...,128:144]=Bm [...,144:160]=Cm
    const float* __restrict__ A_log,
    const us*    __restrict__ g_t,
    us*          __restrict__ y_t)
{
    __shared__ float dvs[T_ + NCH];   // swizzle f(t)=t+(t>>6)
    __shared__ float dxs[T_ + NCH];
    __shared__ float gs [T_ + NCH];
    __shared__ float ys [T_ + NCH];
    __shared__ float Pl[NCH][N_];
    __shared__ float Sl[NCH][N_];

    const int tid = threadIdx.x;
    const int d = blockIdx.x & (D_ - 1);
    const int b = blockIdx.x >> 11;
    const int n = tid & 15;
    const int c = tid >> 4;            // chunk 0..31
    const size_t rb = (size_t)b * T_;
    const size_t cb0 = (size_t)d * ROWS + rb;

    {   // coalesced staging: 2 elems/thread
        int i = tid * 2;
        int fi = i + (i >> 6);
        float2 dv2 = *(const float2*)&delta_t[cb0 + i];
        ushort2 ug = *(const ushort2*)&g_t   [cb0 + i];
        ushort2 ux = *(const ushort2*)&x1tb  [cb0 + i];
        dvs[fi+0] = dv2.x;              dvs[fi+1] = dv2.y;
        dxs[fi+0] = dv2.x * us2f(ux.x); dxs[fi+1] = dv2.y * us2f(ux.y);
        gs [fi+0] = us2f(ug.x);         gs [fi+1] = us2f(ug.y);
    }
    const float a_coef = -__expf(A_log[d * N_ + n]);
    __syncthreads();

    float P = 1.f, S = 0.f;
    const int t0 = c * CLEN;
#pragma unroll 4
    for (int j = 0; j < CLEN; ++j) {
        int t = t0 + j;
        int ft = t + (t >> 6);
        float Bv = dbc[(rb + t) * NDBC + DTR_ + n];
        float a = __expf(dvs[ft] * a_coef);
        P *= a;
        S = fmaf(a, S, dxs[ft] * Bv);
    }
    Pl[c][n] = P;
    Sl[c][n] = S;
    __syncthreads();

    float h = 0.f;
    for (int c2 = 0; c2 < c; ++c2)
        h = fmaf(Pl[c2][n], h, Sl[c2][n]);

#pragma unroll 4
    for (int j = 0; j < CLEN; ++j) {
        int t = t0 + j;
        int ft = t + (t >> 6);
        size_t r = rb + t;
        float Bv = dbc[r * NDBC + DTR_ + n];
        float Cv = dbc[r * NDBC + DTR_ + N_ + n];
        float a = __expf(dvs[ft] * a_coef);
        h = fmaf(a, h, dxs[ft] * Bv);
        float part = sum16_dpp(h * Cv);
        if (n == 0) {
            float g = gs[ft];
            float sg = 1.f / (1.f + __expf(-g));
            ys[ft] = part * g * sg;
        }
    }
    __syncthreads();
    {   // coalesced bf16 store of y
        int i = tid * 2;
        int fi = i + (i >> 6);
        ushort2 uy;
        uy.x = f2us(ys[fi+0]); uy.y = f2us(ys[fi+1]);
        *(ushort2*)&y_t[cb0 + i] = uy;
    }
}

extern "C" void kernel_launch(void* const* d_in, const int* in_sizes, int n_in,
                              void* d_out, int out_size, void* d_ws, size_t ws_size,
                              hipStream_t stream)
{
    const float* x      = (const float*)d_in[0];
    const float* rms_w  = (const float*)d_in[1];
    const float* in_W   = (const float*)d_in[2];
    const float* in_b   = (const float*)d_in[3];
    const float* conv_w = (const float*)d_in[4];
    const float* conv_b = (const float*)d_in[5];
    const float* A_log  = (const float*)d_in[6];
    const float* dbc_W  = (const float*)d_in[7];
    const float* dbc_b  = (const float*)d_in[8];
    const float* dup_W  = (const float*)d_in[9];
    const float* dup_b  = (const float*)d_in[10];
    const float* out_W  = (const float*)d_in[11];
    const float* out_b  = (const float*)d_in[12];
    float* out = (float*)d_out;

    // ---- workspace layout (~84 MB; ~94 MB proven available in R1) ----
    float* ws      = (float*)d_ws;
    float* x1pre   = ws;                           // 16 MB fp32 [rows][D], dead after conv
    us* g_rm  = (us*)(x1pre + (size_t)ROWS*D_);    // 8 MB bf16 [rows][D], dead after conv
    us* g_t   = g_rm  + (size_t)ROWS*D_;           // 8 MB bf16 [d][rows]
    float* dbcB    = (float*)(g_t + (size_t)ROWS*D_); // 1.3 MB fp32
    float* delta_t = dbcB + (size_t)ROWS*NDBC;     // 16 MB fp32 [d][rows]
    us* hbf   = (us*)(delta_t + (size_t)ROWS*D_);  // 4 MB
    us* x1cb  = hbf   + (size_t)ROWS*DM_;          // 8 MB [rows][D], dead after dbc-GEMM
    us* x1tb  = x1cb  + (size_t)ROWS*D_;           // 8 MB [d][rows]
    us* dtrb  = x1tb  + (size_t)ROWS*D_;           // 0.5 MB [rows][DTR]
    us* inWt  = dtrb  + (size_t)ROWS*DTR_;         // 8 MB  [4096][1024]
    us* dbcWt = inWt  + (size_t)2*D_*DM_;          // 0.64 MB [160][2048]
    us* dupWt = dbcWt + (size_t)NDBC*D_;           // 0.5 MB [2048][128]
    us* outWt = dupWt + (size_t)D_*DTR_;           // 4 MB  [1024][2048]
    us* y_t   = (us*)x1pre;                        // alias (x1pre dead), [d][rows]
    us* ybf   = x1cb;                              // alias (x1cb dead), [rows][D]

    dim3 tb(32, 8);
    // 1. weight prep
    prep_weights<<<6720, tb, 0, stream>>>(in_W, out_W, dbc_W, dup_W,
                                          inWt, outWt, dbcWt, dupWt);
    // 2. fused rmsnorm -> hbf (bf16)
    rmshbf_kernel<<<ROWS, 256, 0, stream>>>(x, rms_w, hbf);
    // 3. fused in_proj: x1pre fp32 + g_rm bf16 (both row-major)  [2048 x 4096], K=1024
    mgemm<4,false><<<dim3(32, 16), 256, 0, stream>>>(
        hbf, inWt, in_b, x1pre, g_rm, nullptr, ROWS, 2*D_, DM_);
    // 4. conv + silu -> x1cb + x1tb ; g_rm -> g_t transpose
    conv_silu_kernel<<<dim3(D_/32, ROWS/32), tb, 0, stream>>>(
        x1pre, g_rm, conv_w, conv_b, x1cb, x1tb, g_t);
    // 5. dbc = x1c @ dbc_W + dbc_b   [2048 x 160], K=2048 (+bf16 aux cols<128)
    mgemm<3,false><<<dim3(2, 16), 256, 0, stream>>>(
        x1cb, dbcWt, dbc_b, dbcB, dtrb, nullptr, ROWS, NDBC, D_);
    // 6. delta_t = softplus(dup_W^T @ dtr^T + dup_b)  [2048 x 2048], K=128 (cheap softplus)
    mgemm<1,true><<<dim3(16, 16), 256, 0, stream>>>(
        dupWt, dtrb, dup_b, delta_t, nullptr, nullptr, D_, ROWS, DTR_);
    // 7. chunked selective scan + gate -> y_t [d][rows]
    scan_block_kernel<<<B_*D_, 512, 0, stream>>>(delta_t, x1tb, dbcB, A_log, g_t, y_t);
    // 8. y_t -> ybf [rows][D]
    transpose_us<<<dim3(ROWS/32, D_/32), tb, 0, stream>>>(y_t, ybf, D_, ROWS);
    // 9. out = y @ out_W + out_b + residual   [2048 x 1024], K=2048
    mgemm<2,false><<<dim3(8, 16), 256, 0, stream>>>(
        ybf, outWt, out_b, out, nullptr, x, ROWS, DM_, D_);
}

// Round 13
// 329.693 us; speedup vs baseline: 1.5583x; 1.2175x over previous
//
#include <hip/hip_runtime.h>
#include <math.h>

typedef unsigned short us;
typedef __attribute__((ext_vector_type(8))) short frag8;
typedef __attribute__((ext_vector_type(4))) float f4;

#define B_   2
#define T_   1024
#define DM_  1024
#define D_   2048
#define N_   16
#define DTR_ 128
#define NDBC 160           // DTR + 2N
#define ROWS (B_*T_)       // 2048
#define EPS_ 1e-6f
#define NCH  32            // scan chunks per channel
#define CLEN (T_/NCH)      // 32 steps per chunk

__device__ __forceinline__ float us2f(us s){
    return __uint_as_float(((unsigned int)s) << 16);
}
__device__ __forceinline__ us f2us(float f){   // RTN-even fp32->bf16
    unsigned int u = __float_as_uint(f);
    return (us)((u + 0x7FFF + ((u >> 16) & 1)) >> 16);
}

// async global->LDS, 16B per lane. LDS dest is wave-uniform base + lane*16.
__device__ __forceinline__ void async16(const void* g, void* l){
    __builtin_amdgcn_global_load_lds(
        (const __attribute__((address_space(1))) void*)g,
        (__attribute__((address_space(3)))       void*)l, 16, 0, 0);
}

// one DPP row_ror:K accumulate step (dpp_ctrl must be a literal constant)
template<int CTRL>
__device__ __forceinline__ float dpp_add(float x){
    int t = __builtin_amdgcn_update_dpp(0, __float_as_int(x), CTRL, 0xF, 0xF, true);
    return x + __int_as_float(t);
}
// 16-lane sum via DPP row_ror (VALU pipe, no DS ops)
__device__ __forceinline__ float sum16_dpp(float x){
    x = dpp_add<0x128>(x);   // row_ror:8
    x = dpp_add<0x124>(x);   // row_ror:4
    x = dpp_add<0x122>(x);   // row_ror:2
    x = dpp_add<0x121>(x);   // row_ror:1
    return x;
}

// ---- combined weight prep: 4 matrices fp32 [R][C] -> bf16 [C][R] ----
__global__ __launch_bounds__(256) void prep_weights(
    const float* __restrict__ in_W,  const float* __restrict__ out_W,
    const float* __restrict__ dbc_W, const float* __restrict__ dup_W,
    us* __restrict__ inWt, us* __restrict__ outWt,
    us* __restrict__ dbcWt, us* __restrict__ dupWt)
{
    __shared__ us tile[32][33];
    int bid = blockIdx.x;
    const float* src; us* dst; int C, R, TX, rel;
    if (bid < 4096)      { src = in_W;  dst = inWt;  R = 1024; C = 4096; TX = 128; rel = bid; }
    else if (bid < 6144) { src = out_W; dst = outWt; R = 2048; C = 1024; TX = 32;  rel = bid - 4096; }
    else if (bid < 6464) { src = dbc_W; dst = dbcWt; R = 2048; C = 160;  TX = 5;   rel = bid - 6144; }
    else                 { src = dup_W; dst = dupWt; R = 128;  C = 2048; TX = 64;  rel = bid - 6464; }
    int c0 = (rel % TX) * 32, r0 = (rel / TX) * 32;
    int tx = threadIdx.x, ty = threadIdx.y;   // 32 x 8
    for (int i = ty; i < 32; i += 8)
        tile[i][tx] = f2us(src[(size_t)(r0 + i) * C + c0 + tx]);
    __syncthreads();
    for (int i = ty; i < 32; i += 8)
        dst[(size_t)(c0 + i) * R + r0 + tx] = tile[tx][i];
}

// ------------- bf16 [R][C] -> bf16 [C][R] (dims multiples of 32) -------------
__global__ __launch_bounds__(256) void transpose_us(const us* __restrict__ in,
                                                    us* __restrict__ out, int R, int C)
{
    __shared__ us tile[32][33];
    int c0 = blockIdx.x * 32, r0 = blockIdx.y * 32;
    int tx = threadIdx.x, ty = threadIdx.y;   // 32 x 8
    for (int i = ty; i < 32; i += 8)
        tile[i][tx] = in[(size_t)(r0 + i) * C + c0 + tx];
    __syncthreads();
    for (int i = ty; i < 32; i += 8)
        out[(size_t)(c0 + i) * R + r0 + tx] = tile[tx][i];
}

// ---------------- fused RMSNorm -> bf16 h, one block per row ----------------
__global__ __launch_bounds__(256) void rmshbf_kernel(const float* __restrict__ x,
                                                     const float* __restrict__ rms_w,
                                                     us* __restrict__ hbf)
{
    const int row = blockIdx.x;
    const float* xr = x + (size_t)row * DM_;
    const int tid = threadIdx.x;
    float vals[4], ss = 0.f;
#pragma unroll
    for (int i = 0; i < 4; ++i) { vals[i] = xr[tid + i*256]; ss += vals[i]*vals[i]; }
#pragma unroll
    for (int off = 32; off >= 1; off >>= 1) ss += __shfl_xor(ss, off, 64);
    __shared__ float red[4];
    if ((tid & 63) == 0) red[tid >> 6] = ss;
    __syncthreads();
    float scale = rsqrtf((red[0]+red[1]+red[2]+red[3]) / (float)DM_ + EPS_);
#pragma unroll
    for (int i = 0; i < 4; ++i)
        hbf[(size_t)row * DM_ + tid + i*256] = f2us(vals[i] * scale * rms_w[tid + i*256]);
}

// ---------- MFMA GEMM: C[M,N] = A[M,K](bf16) * Bt[N,K](bf16)^T + bias --------
// 128x128 tile / 4 waves; wave 64x64 via 4x4 mfma_f32_16x16x32_bf16.
// Staging via global_load_lds width=16 (m97 ladder step): unpadded [128][64]
// LDS, 2-barrier K-loop. No per-lane predication on B rows: OOB rows (dbc,
// nrow up to 255 vs N=160) read adjacent mapped ws; poisoned acc lands only in
// col>=N tiles which the epilogue discards.
// RB: bias indexed by M-row. EPI 0: fp32. 1: cheap softplus fp32. 2: +resid.
// EPI 3: fp32 + bf16 aux col<DTR. EPI 4: col<D fp32 Cf; col>=D bf16 Caux.
template<int EPI, bool RB>
__global__ __launch_bounds__(256) void mgemm(
    const us*    __restrict__ A,     // [M][K]
    const us*    __restrict__ Bt,    // [N][K]
    const float* __restrict__ bias,
    float*       __restrict__ Cf,
    us*          __restrict__ Caux,
    const float* __restrict__ resid, // EPI==2
    int M, int N, int K)
{
    __shared__ us As[128*64];
    __shared__ us Bs[128*64];
    const int tid = threadIdx.x;
    const int bm = blockIdx.y * 128;
    const int bn = blockIdx.x * 128;
    const int w = tid >> 6, lane = tid & 63;
    const int wr = w >> 1, wc = w & 1;
    const int m16 = lane & 15, quad = lane >> 4;

    f4 acc[4][4];
#pragma unroll
    for (int i = 0; i < 4; ++i)
#pragma unroll
        for (int j = 0; j < 4; ++j)
            acc[i][j] = (f4){0.f, 0.f, 0.f, 0.f};

    for (int k0 = 0; k0 < K; k0 += 64) {
        __syncthreads();   // prior iter's frag reads done before overwrite
#pragma unroll
        for (int q = 0; q < 4; ++q) {
            int cb = (w*4 + q)*64 + lane;       // 16B-chunk id 0..1023
            int row = cb >> 3, c8 = (cb & 7)*8;
            async16(A  + (size_t)(bm + row) * K + k0 + c8, &As[cb*8]);
            async16(Bt + (size_t)(bn + row) * K + k0 + c8, &Bs[cb*8]);
        }
        __syncthreads();   // vmcnt(0) drained here -> LDS valid
#pragma unroll
        for (int ks = 0; ks < 64; ks += 32) {
            frag8 af[4], bfr[4];
#pragma unroll
            for (int i = 0; i < 4; ++i)
                af[i] = *(const frag8*)&As[(wr*64 + i*16 + m16)*64 + ks + quad*8];
#pragma unroll
            for (int j = 0; j < 4; ++j)
                bfr[j] = *(const frag8*)&Bs[(wc*64 + j*16 + m16)*64 + ks + quad*8];
#pragma unroll
            for (int i = 0; i < 4; ++i)
#pragma unroll
                for (int j = 0; j < 4; ++j)
                    acc[i][j] = __builtin_amdgcn_mfma_f32_16x16x32_bf16(af[i], bfr[j], acc[i][j], 0, 0, 0);
        }
    }

#pragma unroll
    for (int i = 0; i < 4; ++i) {
#pragma unroll
        for (int j = 0; j < 4; ++j) {
            int col = bn + wc*64 + j*16 + m16;
            if (col >= N) continue;
            float bvc = RB ? 0.f : bias[col];
#pragma unroll
            for (int r = 0; r < 4; ++r) {
                int row = bm + wr*64 + i*16 + quad*4 + r;
                float v = acc[i][j][r] + (RB ? bias[row] : bvc);
                if constexpr (EPI == 1) {
                    v = fmaxf(v, 0.f) + __logf(1.f + __expf(-fabsf(v)));
                    Cf[(size_t)row * N + col] = v;
                } else if constexpr (EPI == 2) {
                    v += resid[(size_t)row * N + col];
                    Cf[(size_t)row * N + col] = v;
                } else if constexpr (EPI == 3) {
                    Cf[(size_t)row * N + col] = v;
                    if (col < DTR_) Caux[(size_t)row * DTR_ + col] = f2us(v);
                } else if constexpr (EPI == 4) {
                    if (col < D_) Cf  [(size_t)row * D_ + col]        = v;
                    else          Caux[(size_t)row * D_ + (col - D_)] = f2us(v);
                } else {
                    Cf[(size_t)row * N + col] = v;
                }
            }
        }
    }
}

// --- depthwise causal conv (K=4) + SiLU, dual-layout x1 out + g transpose ---
__global__ __launch_bounds__(256) void conv_silu_kernel(
    const float* __restrict__ x1pre,
    const us*    __restrict__ g_rm,
    const float* __restrict__ cw,
    const float* __restrict__ cb,
    us*          __restrict__ x1cb,
    us*          __restrict__ x1tb,
    us*          __restrict__ g_t)
{
    __shared__ us tileX[32][33];
    __shared__ us tileG[32][33];
    const int tx = threadIdx.x, ty = threadIdx.y;   // 32 x 8
    const int d0 = blockIdx.x * 32, r0 = blockIdx.y * 32;
    const int d = d0 + tx;
    const float w0 = cw[d*4+0], w1 = cw[d*4+1], w2 = cw[d*4+2], w3 = cw[d*4+3];
    const float bias = cb[d];
    for (int i = ty; i < 32; i += 8) {
        int row = r0 + i;
        int t = row & (T_ - 1);
        const float* base = x1pre + (size_t)row * D_ + d;
        float acc = bias;
        acc = fmaf(w3, base[0], acc);
        if (t >= 1) acc = fmaf(w2, base[-D_],   acc);
        if (t >= 2) acc = fmaf(w1, base[-2*D_], acc);
        if (t >= 3) acc = fmaf(w0, base[-3*D_], acc);
        float sg = 1.f / (1.f + __expf(-acc));
        us uv = f2us(acc * sg);
        x1cb[(size_t)row * D_ + d] = uv;
        tileX[i][tx] = uv;
        tileG[i][tx] = g_rm[(size_t)row * D_ + d];
    }
    __syncthreads();
    for (int i = ty; i < 32; i += 8) {
        x1tb[(size_t)(d0 + i) * ROWS + r0 + tx] = tileX[tx][i];
        g_t [(size_t)(d0 + i) * ROWS + r0 + tx] = tileG[tx][i];
    }
}

// ------- chunked selective scan + gate, one block per (b,d) channel ----------
__global__ __launch_bounds__(512) void scan_block_kernel(
    const float* __restrict__ delta_t,
    const us*    __restrict__ x1tb,
    const float* __restrict__ dbc,    // [...,128:144]=Bm [...,144:160]=Cm
    const float* __restrict__ A_log,
    const us*    __restrict__ g_t,
    us*          __restrict__ y_t)
{
    __shared__ float dvs[T_ + NCH];   // swizzle f(t)=t+(t>>6)
    __shared__ float dxs[T_ + NCH];
    __shared__ float gs [T_ + NCH];
    __shared__ float ys [T_ + NCH];
    __shared__ float Pl[NCH][N_];
    __shared__ float Sl[NCH][N_];

    const int tid = threadIdx.x;
    const int d = blockIdx.x & (D_ - 1);
    const int b = blockIdx.x >> 11;
    const int n = tid & 15;
    const int c = tid >> 4;            // chunk 0..31
    const size_t rb = (size_t)b * T_;
    const size_t cb0 = (size_t)d * ROWS + rb;

    {   // coalesced staging: 2 elems/thread
        int i = tid * 2;
        int fi = i + (i >> 6);
        float2 dv2 = *(const float2*)&delta_t[cb0 + i];
        ushort2 ug = *(const ushort2*)&g_t   [cb0 + i];
        ushort2 ux = *(const ushort2*)&x1tb  [cb0 + i];
        dvs[fi+0] = dv2.x;              dvs[fi+1] = dv2.y;
        dxs[fi+0] = dv2.x * us2f(ux.x); dxs[fi+1] = dv2.y * us2f(ux.y);
        gs [fi+0] = us2f(ug.x);         gs [fi+1] = us2f(ug.y);
    }
    const float a_coef = -__expf(A_log[d * N_ + n]);
    __syncthreads();

    float P = 1.f, S = 0.f;
    const int t0 = c * CLEN;
#pragma unroll 4
    for (int j = 0; j < CLEN; ++j) {
        int t = t0 + j;
        int ft = t + (t >> 6);
        float Bv = dbc[(rb + t) * NDBC + DTR_ + n];
        float a = __expf(dvs[ft] * a_coef);
        P *= a;
        S = fmaf(a, S, dxs[ft] * Bv);
    }
    Pl[c][n] = P;
    Sl[c][n] = S;
    __syncthreads();

    float h = 0.f;
    for (int c2 = 0; c2 < c; ++c2)
        h = fmaf(Pl[c2][n], h, Sl[c2][n]);

#pragma unroll 4
    for (int j = 0; j < CLEN; ++j) {
        int t = t0 + j;
        int ft = t + (t >> 6);
        size_t r = rb + t;
        float Bv = dbc[r * NDBC + DTR_ + n];
        float Cv = dbc[r * NDBC + DTR_ + N_ + n];
        float a = __expf(dvs[ft] * a_coef);
        h = fmaf(a, h, dxs[ft] * Bv);
        float part = sum16_dpp(h * Cv);
        if (n == 0) {
            float g = gs[ft];
            float sg = 1.f / (1.f + __expf(-g));
            ys[ft] = part * g * sg;
        }
    }
    __syncthreads();
    {   // coalesced bf16 store of y
        int i = tid * 2;
        int fi = i + (i >> 6);
        ushort2 uy;
        uy.x = f2us(ys[fi+0]); uy.y = f2us(ys[fi+1]);
        *(ushort2*)&y_t[cb0 + i] = uy;
    }
}

extern "C" void kernel_launch(void* const* d_in, const int* in_sizes, int n_in,
                              void* d_out, int out_size, void* d_ws, size_t ws_size,
                              hipStream_t stream)
{
    const float* x      = (const float*)d_in[0];
    const float* rms_w  = (const float*)d_in[1];
    const float* in_W   = (const float*)d_in[2];
    const float* in_b   = (const float*)d_in[3];
    const float* conv_w = (const float*)d_in[4];
    const float* conv_b = (const float*)d_in[5];
    const float* A_log  = (const float*)d_in[6];
    const float* dbc_W  = (const float*)d_in[7];
    const float* dbc_b  = (const float*)d_in[8];
    const float* dup_W  = (const float*)d_in[9];
    const float* dup_b  = (const float*)d_in[10];
    const float* out_W  = (const float*)d_in[11];
    const float* out_b  = (const float*)d_in[12];
    float* out = (float*)d_out;

    // ---- workspace layout (~84 MB; 89.3 MB proven available in R1) ----
    float* ws      = (float*)d_ws;
    float* x1pre   = ws;                           // 16 MB fp32 [rows][D], dead after conv
    us* g_rm  = (us*)(x1pre + (size_t)ROWS*D_);    // 8 MB bf16 [rows][D], dead after conv
    us* g_t   = g_rm  + (size_t)ROWS*D_;           // 8 MB bf16 [d][rows]
    float* dbcB    = (float*)(g_t + (size_t)ROWS*D_); // 1.3 MB fp32
    float* delta_t = dbcB + (size_t)ROWS*NDBC;     // 16 MB fp32 [d][rows]
    us* hbf   = (us*)(delta_t + (size_t)ROWS*D_);  // 4 MB
    us* x1cb  = hbf   + (size_t)ROWS*DM_;          // 8 MB [rows][D], dead after dbc-GEMM
    us* x1tb  = x1cb  + (size_t)ROWS*D_;           // 8 MB [d][rows]
    us* dtrb  = x1tb  + (size_t)ROWS*D_;           // 0.5 MB [rows][DTR]
    us* inWt  = dtrb  + (size_t)ROWS*DTR_;         // 8 MB  [4096][1024]
    us* dbcWt = inWt  + (size_t)2*D_*DM_;          // 0.64 MB [160][2048]
    us* dupWt = dbcWt + (size_t)NDBC*D_;           // 0.5 MB [2048][128]
    us* outWt = dupWt + (size_t)D_*DTR_;           // 4 MB  [1024][2048]
    us* y_t   = (us*)x1pre;                        // alias (x1pre dead), [d][rows]
    us* ybf   = x1cb;                              // alias (x1cb dead), [rows][D]

    dim3 tb(32, 8);
    // 1. weight prep
    prep_weights<<<6720, tb, 0, stream>>>(in_W, out_W, dbc_W, dup_W,
                                          inWt, outWt, dbcWt, dupWt);
    // 2. fused rmsnorm -> hbf (bf16)
    rmshbf_kernel<<<ROWS, 256, 0, stream>>>(x, rms_w, hbf);
    // 3. fused in_proj: x1pre fp32 + g_rm bf16 (both row-major)  [2048 x 4096], K=1024
    mgemm<4,false><<<dim3(32, 16), 256, 0, stream>>>(
        hbf, inWt, in_b, x1pre, g_rm, nullptr, ROWS, 2*D_, DM_);
    // 4. conv + silu -> x1cb + x1tb ; g_rm -> g_t transpose
    conv_silu_kernel<<<dim3(D_/32, ROWS/32), tb, 0, stream>>>(
        x1pre, g_rm, conv_w, conv_b, x1cb, x1tb, g_t);
    // 5. dbc = x1c @ dbc_W + dbc_b   [2048 x 160], K=2048 (+bf16 aux cols<128)
    mgemm<3,false><<<dim3(2, 16), 256, 0, stream>>>(
        x1cb, dbcWt, dbc_b, dbcB, dtrb, nullptr, ROWS, NDBC, D_);
    // 6. delta_t = softplus(dup_W^T @ dtr^T + dup_b)  [2048 x 2048], K=128
    mgemm<1,true><<<dim3(16, 16), 256, 0, stream>>>(
        dupWt, dtrb, dup_b, delta_t, nullptr, nullptr, D_, ROWS, DTR_);
    // 7. chunked selective scan + gate -> y_t [d][rows]
    scan_block_kernel<<<B_*D_, 512, 0, stream>>>(delta_t, x1tb, dbcB, A_log, g_t, y_t);
    // 8. y_t -> ybf [rows][D]
    transpose_us<<<dim3(ROWS/32, D_/32), tb, 0, stream>>>(y_t, ybf, D_, ROWS);
    // 9. out = y @ out_W + out_b + residual   [2048 x 1024], K=2048
    mgemm<2,false><<<dim3(8, 16), 256, 0, stream>>>(
        ybf, outWt, out_b, out, nullptr, x, ROWS, DM_, D_);
}